// Round 2
// baseline (4709.005 us; speedup 1.0000x reference)
//
#include <hip/hip_runtime.h>

// LSTM T=128,B=64,I=H=1024,L=8 — diagonal-wavefront schedule over (t,l) stages.
// ws layout: packedW bf16 [L][256 ntile][64 kchunk][64 lane][8]   134,217,728 B
//            xbf    bf16 [T][B][I]                                16,777,216 B
//            bias   f32  [L][4096]                                   131,072 B
//            c_state f32 [L][B][H]                                 2,097,152 B
//            h_buf  bf16 [2][L][B][H]                              2,097,152 B
// total ~155.3 MB of d_ws.

typedef __attribute__((ext_vector_type(8))) short short8;
typedef __attribute__((ext_vector_type(4))) float f32x4;

#define T_ 128
#define B_ 64
#define H_ 1024
#define L_ 8

__device__ __forceinline__ unsigned short f2bf(float f) {
    unsigned u = __builtin_bit_cast(unsigned, f);
    u += 0x7fff + ((u >> 16) & 1);          // round-to-nearest-even
    return (unsigned short)(u >> 16);
}

// Pack Wih|Whh (fp32 [L,4,1024,1024] each) into bf16 B-fragment lane order:
// packed[((l*256+ntile)*64+kchunk)*512 + lane*8 + j] = W[k][n], n=ntile*16+(lane&15),
// k = kchunk*32 + (lane>>4)*8 + j  (k<1024 -> Wih, else Whh).
__global__ void pack_weights(const float* __restrict__ Wih, const float* __restrict__ Whh,
                             unsigned short* __restrict__ packedW) {
    int tid = blockIdx.x * 256 + threadIdx.x;          // 8,388,608 threads
    int lane = tid & 63;
    int kchunk = (tid >> 6) & 63;
    int ntile = (tid >> 12) & 255;
    int l = tid >> 20;
    int n = ntile * 16 + (lane & 15);
    int g = n >> 10;
    int h = n & 1023;
    int kbase = kchunk * 32 + ((lane >> 4) << 3);
    short8 v;
#pragma unroll
    for (int j = 0; j < 8; ++j) {
        int k = kbase + j;
        float w = (k < 1024) ? Wih[(((l * 4 + g) * 1024 + k) << 10) + h]
                             : Whh[(((l * 4 + g) * 1024 + (k - 1024)) << 10) + h];
        v[j] = (short)f2bf(w);
    }
    *(short8*)(packedW + (size_t)tid * 8) = v;
}

__global__ void prep_misc(const float* __restrict__ x, const float* __restrict__ bih,
                          const float* __restrict__ bhh, unsigned short* __restrict__ xbf,
                          float* __restrict__ bias, float* __restrict__ c_state,
                          unsigned short* __restrict__ h_buf) {
    int tid = blockIdx.x * 256 + threadIdx.x;          // 8,388,608 = T*B*I
    xbf[tid] = f2bf(x[tid]);
    if (tid < L_ * 4096) bias[tid] = bih[tid] + bhh[tid];
    if (tid < L_ * B_ * H_) c_state[tid] = 0.f;
    if (tid < 2 * L_ * B_ * H_) h_buf[tid] = 0;
}

// One diagonal d: stages (t = d-l, l) for l in [lmin, lmin+gridDim.y).
// blockIdx.x in [0,32): 32-wide hidden-unit strip. wave = gate.
__global__ __launch_bounds__(256, 2)
void lstm_diag(const unsigned short* __restrict__ packedW,
               const unsigned short* __restrict__ xbf,
               const float* __restrict__ bias,
               float* __restrict__ c_state,
               unsigned short* __restrict__ h_buf,
               float* __restrict__ out,
               int d, int lmin) {
    __shared__ __align__(16) unsigned short Abuf[64 * 264];   // 33792 B (pad 264 -> no LDS conflicts)
    const int l = lmin + blockIdx.y;
    const int t = d - l;
    const int tid = threadIdx.x;
    const int lane = tid & 63;
    const int g = tid >> 6;                 // wave index == gate (i,f,c,o)
    const int u0 = blockIdx.x * 32;
    const int m = lane & 15;
    const int q = lane >> 4;

    const unsigned short* xsrc = (l == 0) ? (xbf + t * (B_ * H_))
                                          : (h_buf + ((t & 1) * L_ + (l - 1)) * (B_ * H_));
    const unsigned short* hsrc = h_buf + (((t + 1) & 1) * L_ + l) * (B_ * H_);

    f32x4 acc[4][2];
#pragma unroll
    for (int mt = 0; mt < 4; ++mt) { acc[mt][0] = (f32x4)0.f; acc[mt][1] = (f32x4)0.f; }

    const int ntile0 = g * 64 + (u0 >> 4);
    // ntile stride = 64 kchunks * 64 lanes * 8 = 32768 shorts  (was 4096 — the round-1 bug)
    const unsigned short* bbase0 = packedW + (((size_t)l * 256 + ntile0) * 32768 + lane * 8);
    const unsigned short* bbase1 = bbase0 + 32768;   // next ntile

    for (int kb = 0; kb < 8; ++kb) {
        __syncthreads();
        const unsigned short* src = (kb < 4) ? (xsrc + kb * 256) : (hsrc + (kb - 4) * 256);
#pragma unroll
        for (int p = 0; p < 8; ++p) {       // stage 64 rows x 256 cols bf16 -> LDS
            int idx = p * 256 + tid;
            int row = idx >> 5;
            int seg = idx & 31;
            short8 v = *(const short8*)(src + row * 1024 + seg * 8);
            *(short8*)(&Abuf[row * 264 + seg * 8]) = v;
        }
        __syncthreads();
#pragma unroll
        for (int c = 0; c < 8; ++c) {
            short8 afr[4];
#pragma unroll
            for (int mt = 0; mt < 4; ++mt)
                afr[mt] = *(const short8*)(&Abuf[(mt * 16 + m) * 264 + c * 32 + q * 8]);
            int kc = kb * 8 + c;
            short8 b0 = *(const short8*)(bbase0 + (size_t)kc * 512);
            short8 b1 = *(const short8*)(bbase1 + (size_t)kc * 512);
#pragma unroll
            for (int mt = 0; mt < 4; ++mt) {
                acc[mt][0] = __builtin_amdgcn_mfma_f32_16x16x32_bf16(afr[mt], b0, acc[mt][0], 0, 0, 0);
                acc[mt][1] = __builtin_amdgcn_mfma_f32_16x16x32_bf16(afr[mt], b1, acc[mt][1], 0, 0, 0);
            }
        }
    }

    __syncthreads();
    float* Gbuf = (float*)Abuf;             // [4 gates][64 b][33 pad] = 33792 B, reuses Abuf
#pragma unroll
    for (int mt = 0; mt < 4; ++mt)
#pragma unroll
        for (int nt = 0; nt < 2; ++nt)
#pragma unroll
            for (int r = 0; r < 4; ++r) {
                int b = mt * 16 + q * 4 + r;          // C/D layout: row=(lane>>4)*4+reg
                int u = nt * 16 + m;                  //             col=lane&15
                Gbuf[(g * 64 + b) * 33 + u] = acc[mt][nt][r];
            }
    __syncthreads();

#pragma unroll
    for (int it = 0; it < 8; ++it) {
        int idx = it * 256 + tid;
        int b = idx >> 5;
        int u = idx & 31;
        int nb = u0 + u;
        float gi = Gbuf[(0 * 64 + b) * 33 + u] + bias[l * 4096 + nb];
        float gf = Gbuf[(1 * 64 + b) * 33 + u] + bias[l * 4096 + 1024 + nb];
        float gc = Gbuf[(2 * 64 + b) * 33 + u] + bias[l * 4096 + 2048 + nb];
        float go = Gbuf[(3 * 64 + b) * 33 + u] + bias[l * 4096 + 3072 + nb];
        float ig = 1.f / (1.f + __expf(-gi));
        float fg = 1.f / (1.f + __expf(-gf));
        float cg = tanhf(gc);
        float og = 1.f / (1.f + __expf(-go));
        int cidx = (l * B_ + b) * H_ + nb;
        float cnew = fg * c_state[cidx] + ig * cg;
        c_state[cidx] = cnew;
        float hnew = og * tanhf(cnew);
        h_buf[((t & 1) * L_ + l) * (B_ * H_) + b * H_ + nb] = f2bf(hnew);
        if (l == 7 && t == 127) out[b * H_ + nb] = hnew;
    }
}

extern "C" void kernel_launch(void* const* d_in, const int* in_sizes, int n_in,
                              void* d_out, int out_size, void* d_ws, size_t ws_size,
                              hipStream_t stream) {
    const float* x   = (const float*)d_in[0];
    const float* Wih = (const float*)d_in[1];
    const float* Whh = (const float*)d_in[2];
    const float* bih = (const float*)d_in[3];
    const float* bhh = (const float*)d_in[4];
    float* out = (float*)d_out;

    char* ws = (char*)d_ws;
    unsigned short* packedW = (unsigned short*)ws;
    unsigned short* xbf     = (unsigned short*)(ws + 134217728);
    float* bias             = (float*)(ws + 134217728 + 16777216);
    float* c_state          = (float*)(ws + 134217728 + 16777216 + 131072);
    unsigned short* h_buf   = (unsigned short*)(ws + 134217728 + 16777216 + 131072 + 2097152);

    hipLaunchKernelGGL(pack_weights, dim3(32768), dim3(256), 0, stream, Wih, Whh, packedW);
    hipLaunchKernelGGL(prep_misc, dim3(32768), dim3(256), 0, stream,
                       x, bih, bhh, xbf, bias, c_state, h_buf);
    for (int d = 0; d <= 134; ++d) {
        int lmin = d > 127 ? d - 127 : 0;
        int lmax = d < 7 ? d : 7;
        hipLaunchKernelGGL(lstm_diag, dim3(32, lmax - lmin + 1), dim3(256), 0, stream,
                           packedW, xbf, bias, c_state, h_buf, out, d, lmin);
    }
}